// Round 3
// 573.880 us; speedup vs baseline: 1.0851x; 1.0851x over previous
//
#include <hip/hip_runtime.h>
#include <stdint.h>

// Problem constants
#define BROWS 16384
#define FDIM  2048
#define NCLS  14
#define ADIM  64
#define NCAT  2176   // 2048 (W_proj) + 14 (W_fc) + 114 zero pad
#define QKN   1792   // 2*C*D

typedef __attribute__((ext_vector_type(8))) short bhalf8_t;   // 8 bf16 (4 VGPRs)
typedef __attribute__((ext_vector_type(4))) float f32x4_t;    // MFMA C/D frag

__device__ __forceinline__ unsigned short f2bf(float f) {
  unsigned int u = __builtin_bit_cast(unsigned int, f);
  u += 0x7fffu + ((u >> 16) & 1u);      // RNE
  return (unsigned short)(u >> 16);
}
__device__ __forceinline__ float bf2f(unsigned short s) {
  return __builtin_bit_cast(float, (unsigned int)s << 16);
}

__device__ __forceinline__ void gl_lds16(const void* g, void* l) {
  __builtin_amdgcn_global_load_lds(
      (const __attribute__((address_space(1))) unsigned int*)g,
      (__attribute__((address_space(3))) unsigned int*)l, 16, 0, 0);
}

// raw barrier with compiler memory fence (NOT __syncthreads: no vmcnt(0) drain)
#define BAR() do { \
    asm volatile("" ::: "memory"); \
    __builtin_amdgcn_s_barrier(); \
    asm volatile("" ::: "memory"); \
  } while (0)

// ---------------- elementwise prep ----------------

__global__ void cast8_bf16(const float* __restrict__ src,
                           unsigned short* __restrict__ dst, int n8) {
  int t = blockIdx.x * 256 + threadIdx.x;
  if (t >= n8) return;
  const float4* s = (const float4*)src + 2 * (size_t)t;
  float4 a = s[0], b = s[1];
  bhalf8_t o;
  o[0] = f2bf(a.x); o[1] = f2bf(a.y); o[2] = f2bf(a.z); o[3] = f2bf(a.w);
  o[4] = f2bf(b.x); o[5] = f2bf(b.y); o[6] = f2bf(b.z); o[7] = f2bf(b.w);
  *((bhalf8_t*)dst + t) = o;
}

// concatenated weight [NCAT, FDIM] bf16: rows 0..2047 = W_proj, 2048..2061 = W_fc, rest 0
__global__ void build_wcat(const float* __restrict__ Wp, const float* __restrict__ Wf,
                           unsigned short* __restrict__ dst) {
  int row = blockIdx.x;            // [0, NCAT)
  int c8 = threadIdx.x * 8;        // 256*8 == 2048
  const float* src = nullptr;
  if (row < 2048) src = Wp + (size_t)row * FDIM + c8;
  else if (row < 2048 + NCLS) src = Wf + (size_t)(row - 2048) * FDIM + c8;
  bhalf8_t o = {0,0,0,0,0,0,0,0};
  if (src) {
    float4 a = *(const float4*)src, b = *(const float4*)(src + 4);
    o[0] = f2bf(a.x); o[1] = f2bf(a.y); o[2] = f2bf(a.z); o[3] = f2bf(a.w);
    o[4] = f2bf(b.x); o[5] = f2bf(b.y); o[6] = f2bf(b.z); o[7] = f2bf(b.w);
  }
  *(bhalf8_t*)(dst + (size_t)row * FDIM + c8) = o;
}

// ---------------- 256x256 8-phase MFMA GEMM (T1+T2+T3+T4+T5) ----------------
// BM=BN=256, BK=64, 512 thr (8 waves 2Mx4N), per-wave 128x64 out, acc[8][4].
// LDS 128 KiB: L[buf][A/B][half][128*64] bf16; chunk^(row&7) XOR swizzle
// (verified conflict-free in the 128^2 predecessor), applied via pre-swizzled
// global source (gl_lds dest stays linear) + swizzled ds_read address.
// Per K-tile: 4 phases {ds_read frags | stage 1 half-tile | bar |
// setprio(1) 8xMFMA(x2 k-slices) setprio(0) | bar}. Staging lifetimes:
//   P0/P1: A(u+1) -> buf^1 (A region dead since prev iter's P2)
//   P2/P3: B(u+2) -> buf   (B region dead after this iter's P1 reads)
// One s_waitcnt vmcnt(4) per K-tile (at P3). In-flight there (issue order):
// B(u+1)x4, A(u+1)x4, B(u+2)x4 = 12 -> drains oldest 8 (all of iter u+1's
// data), leaves B(u+2) in flight. Tail: clamped dummy stages keep the count
// uniform; vmcnt(0) after the loop drains them before epilogue/exit.
// MODE 0: cols<2048 -> bf16 h +bias +BN atomics; col tile 8 -> fp32 logits.
// MODE 1: plain bf16 store.

template<int MODE>
__global__ __launch_bounds__(512, 2) void gemm256_bt(
    const unsigned short* __restrict__ A, const unsigned short* __restrict__ Bw,
    const float* __restrict__ bp, const float* __restrict__ bfc,
    unsigned short* __restrict__ Cb, float* __restrict__ logits,
    float* __restrict__ colsum, float* __restrict__ colsq,
    int K, int lda, int ldb, int ldc, int nBr)
{
  __shared__ unsigned short L[2][2][2][8192];   // [buf][A/B][half][128*64] = 128 KiB

  const int t = threadIdx.x;
  const int lane = t & 63;
  const int wv = t >> 6;
  const int m = lane & 15, quad = lane >> 4;
  const int wm = wv >> 2, wn = wv & 3;

  // T1: bijective XCD swizzle (grid % 8 == 0 by construction)
  const int nwg = gridDim.x;
  const int wg = ((blockIdx.x & 7) * (nwg >> 3)) + (blockIdx.x >> 3);
  const int bx = wg & 63;                 // M/256 == 64
  const int by = wg >> 6;
  const int rowBase = bx << 8;
  const int colBase = by << 8;

  // ds_read fragment offsets (shorts): row group r=16x+m, slot = chunk^(r&7)=chunk^(m&7)
  const int bO = (wn & 1) << 12;          // B 64-row subregion offset (64*64 shorts)
  const int ofs0 = m * 64 + ((quad ^ (m & 7)) << 3);   // k-slice 0: chunk quad
  const int ofs1 = ofs0 ^ 32;                          // k-slice 1: chunk quad+4

  // staging: slot s = i*512 + t; r = s>>3, stored chunk = (s&7)^(r&7)
  const int r0 = t >> 3;
  const int q8 = ((t ^ r0) & 7) << 3;     // source chunk element offset in row
  const int ldD = t << 3;                 // LDS dest (shorts); second issue +4096
  const unsigned int aOff =
      (unsigned int)(rowBase + r0) * (unsigned int)lda + (unsigned int)q8;
  unsigned int bOff00, bOff01, bOff10, bOff11;
  {
    int rr;
    rr = colBase + r0;        if (rr > nBr - 1) rr = nBr - 1;
    bOff00 = (unsigned int)rr * (unsigned int)ldb + q8;
    rr = colBase + 64 + r0;   if (rr > nBr - 1) rr = nBr - 1;
    bOff01 = (unsigned int)rr * (unsigned int)ldb + q8;
    rr = colBase + 128 + r0;  if (rr > nBr - 1) rr = nBr - 1;
    bOff10 = (unsigned int)rr * (unsigned int)ldb + q8;
    rr = colBase + 192 + r0;  if (rr > nBr - 1) rr = nBr - 1;
    bOff11 = (unsigned int)rr * (unsigned int)ldb + q8;
  }

#define STAGEA0(b, kb) do { \
    gl_lds16(A + aOff + (unsigned int)(kb), &L[b][0][0][ldD]); \
    gl_lds16(A + aOff + (unsigned int)(64 * lda) + (unsigned int)(kb), &L[b][0][0][ldD + 4096]); \
  } while (0)
#define STAGEA1(b, kb) do { \
    gl_lds16(A + aOff + (unsigned int)(128 * lda) + (unsigned int)(kb), &L[b][0][1][ldD]); \
    gl_lds16(A + aOff + (unsigned int)(192 * lda) + (unsigned int)(kb), &L[b][0][1][ldD + 4096]); \
  } while (0)
#define STAGEB0(b, kb) do { \
    gl_lds16(Bw + bOff00 + (unsigned int)(kb), &L[b][1][0][ldD]); \
    gl_lds16(Bw + bOff01 + (unsigned int)(kb), &L[b][1][0][ldD + 4096]); \
  } while (0)
#define STAGEB1(b, kb) do { \
    gl_lds16(Bw + bOff10 + (unsigned int)(kb), &L[b][1][1][ldD]); \
    gl_lds16(Bw + bOff11 + (unsigned int)(kb), &L[b][1][1][ldD + 4096]); \
  } while (0)

  // fragment loads (named regs, literal offsets only)
#define RDA(v, roff) \
    v##_0 = *(const bhalf8_t*)&LA[(roff) + ofs0]; \
    v##_1 = *(const bhalf8_t*)&LA[(roff) + ofs1];
#define RDB(v, roff) \
    v##_0 = *(const bhalf8_t*)&LB[(roff) + ofs0]; \
    v##_1 = *(const bhalf8_t*)&LB[(roff) + ofs1];
#define MM(i, j, av, bv) \
    acc[i][j] = __builtin_amdgcn_mfma_f32_16x16x32_bf16(av##_0, bv##_0, acc[i][j], 0, 0, 0); \
    acc[i][j] = __builtin_amdgcn_mfma_f32_16x16x32_bf16(av##_1, bv##_1, acc[i][j], 0, 0, 0);

  f32x4_t acc[8][4];
#pragma unroll
  for (int i = 0; i < 8; ++i)
#pragma unroll
    for (int j = 0; j < 4; ++j) acc[i][j] = (f32x4_t){0.f, 0.f, 0.f, 0.f};

  const int NT = K >> 6;

  // prologue: K0 fully -> buf0; B of K1 -> buf1. vmcnt(4) completes K0 (8 oldest).
  STAGEA0(0, 0);
  STAGEA1(0, 0);
  STAGEB0(0, 0);
  STAGEB1(0, 0);
  {
    const int kb1 = (NT > 1) ? 64 : 0;
    STAGEB0(1, kb1);
    STAGEB1(1, kb1);
  }
  asm volatile("s_waitcnt vmcnt(4)" ::: "memory");
  BAR();

  for (int u = 0; u < NT; ++u) {
    const int buf = u & 1;
    const unsigned short* LA = &L[buf][0][wm][0];
    const unsigned short* LB = &L[buf][1][wn >> 1][bO];
    const int kbA = (u + 1 < NT) ? (u + 1) << 6 : 0;   // tail: clamped dummy
    const int kbB = (u + 2 < NT) ? (u + 2) << 6 : 0;

    bhalf8_t a0_0, a0_1, a1_0, a1_1, a2_0, a2_1, a3_0, a3_1;
    bhalf8_t b0_0, b0_1, b1_0, b1_1, b2_0, b2_1, b3_0, b3_1;

    // ---- P0: rd A rows 0..63 + B rows 0..31; stage A0(u+1) ----
    RDA(a0, 0);     RDA(a1, 1024);  RDA(a2, 2048);  RDA(a3, 3072);
    RDB(b0, 0);     RDB(b1, 1024);
    if (buf) { STAGEA0(0, kbA); } else { STAGEA0(1, kbA); }
    BAR();
    __builtin_amdgcn_s_setprio(1);
    MM(0, 0, a0, b0); MM(0, 1, a0, b1);
    MM(1, 0, a1, b0); MM(1, 1, a1, b1);
    MM(2, 0, a2, b0); MM(2, 1, a2, b1);
    MM(3, 0, a3, b0); MM(3, 1, a3, b1);
    __builtin_amdgcn_s_setprio(0);
    BAR();

    // ---- P1: rd B rows 32..63; stage A1(u+1) ----
    RDB(b2, 2048);  RDB(b3, 3072);
    if (buf) { STAGEA1(0, kbA); } else { STAGEA1(1, kbA); }
    BAR();
    __builtin_amdgcn_s_setprio(1);
    MM(0, 2, a0, b2); MM(0, 3, a0, b3);
    MM(1, 2, a1, b2); MM(1, 3, a1, b3);
    MM(2, 2, a2, b2); MM(2, 3, a2, b3);
    MM(3, 2, a3, b2); MM(3, 3, a3, b3);
    __builtin_amdgcn_s_setprio(0);
    BAR();

    // ---- P2: rd A rows 64..127 (reuse a-regs); stage B0(u+2) ----
    RDA(a0, 4096);  RDA(a1, 5120);  RDA(a2, 6144);  RDA(a3, 7168);
    if (buf) { STAGEB0(1, kbB); } else { STAGEB0(0, kbB); }
    BAR();
    __builtin_amdgcn_s_setprio(1);
    MM(4, 0, a0, b0); MM(4, 1, a0, b1);
    MM(5, 0, a1, b0); MM(5, 1, a1, b1);
    MM(6, 0, a2, b0); MM(6, 1, a2, b1);
    MM(7, 0, a3, b0); MM(7, 1, a3, b1);
    __builtin_amdgcn_s_setprio(0);
    BAR();

    // ---- P3: stage B1(u+2); counted vmcnt -> iter u+1's 8 loads complete ----
    if (buf) { STAGEB1(1, kbB); } else { STAGEB1(0, kbB); }
    BAR();
    __builtin_amdgcn_s_setprio(1);
    MM(4, 2, a0, b2); MM(4, 3, a0, b3);
    MM(5, 2, a1, b2); MM(5, 3, a1, b3);
    MM(6, 2, a2, b2); MM(6, 3, a2, b3);
    MM(7, 2, a3, b2); MM(7, 3, a3, b3);
    __builtin_amdgcn_s_setprio(0);
    asm volatile("s_waitcnt vmcnt(4)" ::: "memory");
    BAR();
  }
  asm volatile("s_waitcnt vmcnt(0)" ::: "memory");   // drain tail dummies

#undef STAGEA0
#undef STAGEA1
#undef STAGEB0
#undef STAGEB1
#undef RDA
#undef RDB
#undef MM

  // epilogue: C/D layout col = lane&15 (+16*ni +64*wn), row = quad*4 + r (+16*mi +128*wm)
  if (MODE == 0) {
    if (colBase < 2048) {
#pragma unroll
      for (int ni = 0; ni < 4; ++ni) {
        const int gcol = colBase + wn * 64 + ni * 16 + m;
        const float bv = bp[gcol];
        float s = 0.f, qq = 0.f;
#pragma unroll
        for (int mi = 0; mi < 8; ++mi) {
          const size_t grow = (size_t)(rowBase + wm * 128 + mi * 16 + quad * 4);
#pragma unroll
          for (int r = 0; r < 4; ++r) {
            float v = acc[mi][ni][r] + bv;
            Cb[(grow + r) * (size_t)ldc + gcol] = f2bf(v);
            s += v; qq += v * v;
          }
        }
        s += __shfl_xor(s, 16, 64); s += __shfl_xor(s, 32, 64);
        qq += __shfl_xor(qq, 16, 64); qq += __shfl_xor(qq, 32, 64);
        if (quad == 0) { atomicAdd(&colsum[gcol], s); atomicAdd(&colsq[gcol], qq); }
      }
    } else if (wn == 0) {   // logits tile: rel cols 0..15 (ni==0), waves 0 & 4
      const float bv = (m < NCLS) ? bfc[m] : 0.f;
#pragma unroll
      for (int mi = 0; mi < 8; ++mi) {
        const size_t grow = (size_t)(rowBase + wm * 128 + mi * 16 + quad * 4);
#pragma unroll
        for (int r = 0; r < 4; ++r)
          logits[(grow + r) * 16 + m] = acc[mi][0][r] + bv;
      }
    }
  } else {
#pragma unroll
    for (int ni = 0; ni < 4; ++ni) {
      const int gcol = colBase + wn * 64 + ni * 16 + m;
#pragma unroll
      for (int mi = 0; mi < 8; ++mi) {
        const size_t grow = (size_t)(rowBase + wm * 128 + mi * 16 + quad * 4);
#pragma unroll
        for (int r = 0; r < 4; ++r)
          Cb[(grow + r) * (size_t)ldc + gcol] = f2bf(acc[mi][ni][r]);
      }
    }
  }
}

// ---------------- BatchNorm ----------------

__global__ void bn_finalize(const float* __restrict__ cs, const float* __restrict__ cq,
                            const float* __restrict__ g, const float* __restrict__ bt,
                            float* __restrict__ scale, float* __restrict__ shift) {
  int c = blockIdx.x * 256 + threadIdx.x;
  if (c >= FDIM) return;
  const float inv = 1.f / (float)BROWS;
  float mu = cs[c] * inv;
  float var = cq[c] * inv - mu * mu;
  float sc = g[c] * rsqrtf(var + 1e-5f);
  scale[c] = sc;
  shift[c] = bt[c] - mu * sc;
}

// in-place: h = bf16(relu(h*scale + shift)), bf16 [B, FDIM]
__global__ void bn_apply(unsigned short* __restrict__ hb, const float* __restrict__ sc,
                         const float* __restrict__ sh) {
  int t = blockIdx.x * 256 + threadIdx.x;
  int row = t >> 8;
  int c8 = (t & 255) << 3;
  unsigned short* p = hb + (size_t)row * FDIM + c8;
  bhalf8_t v = *(bhalf8_t*)p;
  float4 s0 = *(const float4*)(sc + c8), s1 = *(const float4*)(sc + c8 + 4);
  float4 h0 = *(const float4*)(sh + c8), h1 = *(const float4*)(sh + c8 + 4);
  bhalf8_t o;
  o[0] = f2bf(fmaxf(bf2f((unsigned short)v[0]) * s0.x + h0.x, 0.f));
  o[1] = f2bf(fmaxf(bf2f((unsigned short)v[1]) * s0.y + h0.y, 0.f));
  o[2] = f2bf(fmaxf(bf2f((unsigned short)v[2]) * s0.z + h0.z, 0.f));
  o[3] = f2bf(fmaxf(bf2f((unsigned short)v[3]) * s0.w + h0.w, 0.f));
  o[4] = f2bf(fmaxf(bf2f((unsigned short)v[4]) * s1.x + h1.x, 0.f));
  o[5] = f2bf(fmaxf(bf2f((unsigned short)v[5]) * s1.y + h1.y, 0.f));
  o[6] = f2bf(fmaxf(bf2f((unsigned short)v[6]) * s1.z + h1.z, 0.f));
  o[7] = f2bf(fmaxf(bf2f((unsigned short)v[7]) * s1.w + h1.w, 0.f));
  *(bhalf8_t*)p = o;
}

// ---------------- attention epilogue: one wave per row ----------------
__global__ __launch_bounds__(256) void attn_ep(
    const unsigned short* __restrict__ qk, const float* __restrict__ logits,
    const float* __restrict__ gamma, float* __restrict__ out)
{
  const int lane = threadIdx.x & 63;
  const int wv = threadIdx.x >> 6;
  const int b = blockIdx.x * 4 + wv;
  const int m = lane & 15, quad = lane >> 4;
  const unsigned short* qrow = qk + (size_t)b * QKN;
  f32x4_t acc = (f32x4_t){0.f, 0.f, 0.f, 0.f};
#pragma unroll
  for (int ks = 0; ks < 2; ++ks) {
    bhalf8_t af = {0,0,0,0,0,0,0,0}, bf = {0,0,0,0,0,0,0,0};
    if (m < NCLS) {
      af = *(const bhalf8_t*)(qrow + m * 64 + ks * 32 + quad * 8);
      bf = *(const bhalf8_t*)(qrow + 896 + m * 64 + ks * 32 + quad * 8);
    }
    acc = __builtin_amdgcn_mfma_f32_16x16x32_bf16(af, bf, acc, 0, 0, 0);
  }
  float logit_e = (m < NCLS) ? logits[(size_t)b * 16 + m] : 0.f;
  float sig = 1.f / (1.f + __expf(-logit_e));
  float corr[4];
#pragma unroll
  for (int r = 0; r < 4; ++r) {
    int c = quad * 4 + r;
    float diag = __shfl(acc[r], (lane & 48) + c, 64);
    float a = acc[r] - diag;
    float av = (m < NCLS) ? fabsf(a) : 0.f;
    av = fmaxf(av, __shfl_xor(av, 1, 64));
    av = fmaxf(av, __shfl_xor(av, 2, 64));
    av = fmaxf(av, __shfl_xor(av, 4, 64));
    av = fmaxf(av, __shfl_xor(av, 8, 64));
    float v = (m < NCLS) ? (a / av) * sig : 0.f;
    v += __shfl_xor(v, 1, 64);
    v += __shfl_xor(v, 2, 64);
    v += __shfl_xor(v, 4, 64);
    v += __shfl_xor(v, 8, 64);
    corr[r] = v;
  }
  if (m == 0) {
#pragma unroll
    for (int r = 0; r < 4; ++r) {
      int c = quad * 4 + r;
      if (c < NCLS) {
        float lc = logits[(size_t)b * 16 + c];
        out[(size_t)b * NCLS + c] = lc + gamma[c] * corr[r];
      }
    }
  }
}

// ---------------- launch ----------------

extern "C" void kernel_launch(void* const* d_in, const int* in_sizes, int n_in,
                              void* d_out, int out_size, void* d_ws, size_t ws_size,
                              hipStream_t stream) {
  const float* features = (const float*)d_in[0];
  const float* W_proj   = (const float*)d_in[1];
  const float* b_proj   = (const float*)d_in[2];
  const float* bn_gamma = (const float*)d_in[3];
  const float* bn_beta  = (const float*)d_in[4];
  const float* W_qk     = (const float*)d_in[5];
  const float* gamma    = (const float*)d_in[6];
  const float* W_fc     = (const float*)d_in[7];
  const float* b_fc     = (const float*)d_in[8];
  float* out = (float*)d_out;

  char* ws = (char*)d_ws;
  unsigned short* featC   = (unsigned short*)ws;                  //  67,108,864 B
  unsigned short* hbuf    = (unsigned short*)(ws + 67108864);     //  67,108,864 B
  unsigned short* WcatC   = (unsigned short*)(ws + 134217728);    //   8,912,896 B
  unsigned short* WqkC    = (unsigned short*)(ws + 143130624);    //   7,340,032 B
  unsigned short* qkC     = (unsigned short*)(ws + 150470656);    //  58,720,256 B
  float*          logitsB = (float*)(ws + 209190912);             //   1,048,576 B
  float*          colsum  = (float*)(ws + 210239488);             //       8,192 B
  float*          colsq   = (float*)(ws + 210247680);             //       8,192 B
  float*          scalev  = (float*)(ws + 210255872);             //       8,192 B
  float*          shiftv  = (float*)(ws + 210264064);             //       8,192 B

  hipMemsetAsync(colsum, 0, 16384, stream);

  cast8_bf16<<<16384, 256, 0, stream>>>(features, featC, (BROWS * FDIM) / 8);
  build_wcat<<<NCAT, 256, 0, stream>>>(W_proj, W_fc, WcatC);
  cast8_bf16<<<1792, 256, 0, stream>>>(W_qk, WqkC, (QKN * FDIM) / 8);

  // GEMM1: 64 x 9 tiles of 256^2 (cols 2048..2303 = logits tile, pad clamped)
  gemm256_bt<0><<<576, 512, 0, stream>>>(
      featC, WcatC, b_proj, b_fc, hbuf, logitsB, colsum, colsq,
      FDIM, FDIM, FDIM, FDIM, NCAT);

  bn_finalize<<<8, 256, 0, stream>>>(colsum, colsq, bn_gamma, bn_beta, scalev, shiftv);
  bn_apply<<<16384, 256, 0, stream>>>(hbuf, scalev, shiftv);

  // GEMM2: 64 x 7 tiles of 256^2
  gemm256_bt<1><<<448, 512, 0, stream>>>(
      hbuf, WqkC, nullptr, nullptr, qkC, nullptr, nullptr, nullptr,
      FDIM, FDIM, FDIM, QKN, QKN);

  attn_ep<<<BROWS / 4, 256, 0, stream>>>(qkC, logitsB, gamma, out);
}